// Round 8
// baseline (242.028 us; speedup 1.0000x reference)
//
#include <hip/hip_runtime.h>
#include <math.h>

#define NN 100000
#define NE 1250000
#define DIN 64
#define DHID 128
#define DO2 64   // concat(mu|lv)
#define DOUT 32

#define NBIN 256
#define BINW ((NN + NBIN - 1) / NBIN)   // 391
#define NSEG 153                        // = ceil(NE / P1_EPB) scatter blocks
#define C2 80                           // per-(bin,block) cell capacity; binom(8192,1/256) mean 32, 8.5-sigma
#define PADESRC 10944                   // per-bin esrc region (max padded 8037), mult of 8
#define P1_THREADS 1024
#define P1_EPT 8
#define P1_EPB (P1_THREADS * P1_EPT)    // 8192

typedef unsigned int uint;
typedef unsigned short ushort;
typedef __attribute__((ext_vector_type(8))) short bf16x8;   // 8 bf16 = 4 VGPR (MFMA A/B frag)
typedef __attribute__((ext_vector_type(4))) float f32x4;    // MFMA C/D frag

#define MFMA16(A, B, C) __builtin_amdgcn_mfma_f32_16x16x32_bf16(A, B, C, 0, 0, 0)

__device__ __forceinline__ ushort f2bf(float f) {
    uint u = __float_as_uint(f);
    uint r = (u + 0x7fffu + ((u >> 16) & 1u)) >> 16;   // RNE
    return (ushort)r;
}
__device__ __forceinline__ uint pack2(float a, float b) {
    return (uint)f2bf(a) | ((uint)f2bf(b) << 16);
}
__device__ __forceinline__ float bflo(uint p) { return __uint_as_float(p << 16); }
__device__ __forceinline__ float bfhi(uint p) { return __uint_as_float(p & 0xffff0000u); }

// stage2 k-permutation: feature index fed at MFMA k-position k.
// k bits: [ks:5-6 | q:3-4 | j:0-2]  ->  n = 32ks + 16*(j>>2) + 4q + (j&3)
__device__ __forceinline__ int nofk(int k) {
    return (k & 3) | (((k >> 3) & 3) << 2) | (((k >> 2) & 1) << 4) | ((k >> 5) << 5);
}

// accumulate 8 bf16 features from a packed uint4 row segment
#define ACC8(A, P) do { \
    A##0 += bflo((P).x); A##1 += bfhi((P).x); \
    A##2 += bflo((P).y); A##3 += bfhi((P).y); \
    A##4 += bflo((P).z); A##5 += bfhi((P).z); \
    A##6 += bflo((P).w); A##7 += bfhi((P).w); } while (0)

// ---------- direct scatter into per-(bin,block) private cells + global degree count ----------
// ebin[(b*NSEG + blk)*C2 + rank] = (src<<9)|localdst ; cnt[b*NSEG + blk] = count.
// deg[d] accumulated via device-scope atomics (replaces finalize's cell-hist pass).
__global__ __launch_bounds__(P1_THREADS) void scatter_direct(const int* __restrict__ src,
                                                             const int* __restrict__ dst,
                                                             int* __restrict__ deg,
                                                             uint* __restrict__ ebin,
                                                             int* __restrict__ cnt, int n) {
    __shared__ int hist[NBIN];
    int tid = threadIdx.x;
    if (tid < NBIN) hist[tid] = 0;
    __syncthreads();
    int bi = blockIdx.x;
    int base = bi * P1_EPB;
#pragma unroll
    for (int j = 0; j < P1_EPT; j++) {
        int i = base + j * P1_THREADS + tid;
        if (i < n) {
            int d = dst[i];
            int bb = d / BINW;
            uint e = ((uint)src[i] << 9) | (uint)(d - bb * BINW);
            atomicAdd(&deg[d], 1);
            int rk = atomicAdd(&hist[bb], 1);
            if (rk < C2) ebin[((size_t)bb * NSEG + bi) * C2 + rk] = e;
        }
    }
    __syncthreads();
    if (tid < NBIN) cnt[tid * NSEG + bi] = min(hist[tid], C2);
}

// ---------- merged finalize: deg -> dis/prange/esrc scatter + x-cast + weight prep ----------
// xb flat: [node][32 uints] = bf16 feats (row NN = zero padding target).
// Weight layout (ushort idx in Wall):
//   [0,8192)      W1 hi  frag fr=t*2+ks: [(fr*64+lane)*8+e] = hi(W1[k*DHID+row]),
//                 row=16t+(lane&15), k=ks*32+(lane>>4)*8+e
//   [8192,16384)  W1 lo (residual)
//   [16384,24576) Wc hi  frag fr=t2*4+ks: nout=16t2+(lane&15), kpos=ks*32+(lane>>4)*8+e,
//                 h=nofk(kpos), hi(Wcat[h][nout]); Wcat = concat cols (Wmu|Wlv)
//   [24576,32768) Wc lo
__global__ __launch_bounds__(512) void finalize_prep(const uint* __restrict__ ebin,
                                                     const int* __restrict__ cnt,
                                                     const int* __restrict__ deg,
                                                     const float* __restrict__ x,
                                                     const float* __restrict__ W1,
                                                     const float* __restrict__ Wmu,
                                                     const float* __restrict__ Wlv,
                                                     float* __restrict__ dis,
                                                     int2* __restrict__ prange,
                                                     int* __restrict__ esrc,
                                                     uint* __restrict__ xb,
                                                     ushort* __restrict__ Wall) {
    __shared__ int hh[BINW];
    __shared__ int base_s[BINW];
    __shared__ int cur_s[BINW];
    __shared__ float dd[BINW];
    int b = blockIdx.x;
    int tid = threadIdx.x;
    int v0 = b * BINW;
    int nv = min(BINW, NN - v0);
    int pbase = PADESRC * b;                        // 8-aligned by construction
    int c = (tid < nv) ? deg[v0 + tid] : 0;         // degree straight from atomics
    int p = (c + 7) & ~7;
    if (tid < BINW) { hh[tid] = (tid < nv) ? p : 0; cur_s[tid] = 0; }
    __syncthreads();
    for (int off = 1; off < BINW; off <<= 1) {      // inclusive scan of padded counts
        int t = (tid < nv && tid >= off) ? hh[tid - off] : 0;
        __syncthreads();
        if (tid < nv) hh[tid] += t;
        __syncthreads();
    }
    if (tid < nv) {
        int base = pbase + hh[tid] - p;
        base_s[tid] = base;
        prange[v0 + tid] = make_int2(base, base + p);
        float dv = rsqrtf((float)c + 1.0f);
        dis[v0 + tid] = dv;
        dd[tid] = dv;
        for (int j = c; j < p; j++) esrc[base + j] = NN;   // node tail padding
    }
    __syncthreads();
    // scatter src indices from this bin's cells
    int wv = tid >> 6, ln = tid & 63;
    for (int s = wv; s < NSEG; s += 8) {
        int m = cnt[b * NSEG + s];
        const uint* cell = ebin + ((size_t)b * NSEG + s) * C2;
        for (int j = ln; j < m; j += 64) {
            uint e = cell[j];
            int l = (int)(e & 511u);
            int pos = base_s[l] + atomicAdd(&cur_s[l], 1);
            esrc[pos] = (int)(e >> 9);
        }
    }
    // cast + pre-scale this bin's x rows: xb[row] = bf16(dis_row * x[row])
    for (int idx = tid; idx < nv * 8; idx += 512) {
        int r = idx >> 3, q = idx & 7;
        float dv = dd[r];
        int row = v0 + r;
        const float4* xs = (const float4*)(x + (size_t)row * 64 + q * 8);
        float4 u0 = xs[0], u1 = xs[1];
        uint4 o;
        o.x = pack2(dv * u0.x, dv * u0.y);
        o.y = pack2(dv * u0.z, dv * u0.w);
        o.z = pack2(dv * u1.x, dv * u1.y);
        o.w = pack2(dv * u1.z, dv * u1.w);
        *(uint4*)(xb + (size_t)row * 32 + q * 4) = o;
    }
    if (b == NBIN - 1 && tid < 32) xb[(size_t)NN * 32 + tid] = 0;   // zero padding row
    // weight prep: 64 items per block
    if (tid < 64) {
        int i = b * 64 + tid;                        // < 16384
        if (i < 8192) {
            int lane = (i >> 3) & 63, e = i & 7;
            int fr = i >> 9;                 // t*2+ks
            int t = fr >> 1, ks = fr & 1;
            int row = 16 * t + (lane & 15);
            int k = ks * 32 + (lane >> 4) * 8 + e;
            float w = W1[k * DHID + row];
            ushort hi = f2bf(w);
            Wall[i] = hi;
            Wall[8192 + i] = f2bf(w - bflo((uint)hi));
        } else {
            int ii = i - 8192;
            int lane = (ii >> 3) & 63, e = ii & 7;
            int fr = ii >> 9;                // t2*4+ks
            int t2 = fr >> 2, ks = fr & 3;
            int nout = 16 * t2 + (lane & 15);
            int kpos = ks * 32 + (lane >> 4) * 8 + e;
            int h = nofk(kpos);
            float w = (nout < DOUT) ? Wmu[h * DOUT + nout] : Wlv[h * DOUT + (nout - DOUT)];
            ushort hi = f2bf(w);
            Wall[16384 + ii] = hi;
            Wall[24576 + ii] = f2bf(w - bflo((uint)hi));
        }
    }
}

// ---------- 16-lanes-per-node gather core (4 nodes/wave), flat 128B rows ----------
// Lane bits: [5:4]=node group, [3]=edge-parallel slot, [2:0]=feature quad.
// All 16 shfls hoisted into svals (static reg indices). Batch 2 / tail use PER-LANE
// predicates (deg uniform within 16-lane group -> exec-masked skip, no wasted loads).
// Self-loop pv LOADED early, ADDED ONCE post-reduce (R3 lesson).
#define GATHER_CORE(TBL)                                                            \
    int tid = threadIdx.x;                                                          \
    int lane = tid & 63;                                                            \
    int sub = lane & 15;                                                            \
    int epar = sub >> 3;                                                            \
    int f4 = (sub & 7) * 4;                                                         \
    int nlb = lane & 48;                                                            \
    int v = blockIdx.x * 16 + (tid >> 4);            /* NN = 6250*16 exactly */     \
    int2 rng = prange[v];                                                           \
    int beg = rng.x, nb = rng.y - rng.x;             /* nb multiple of 8 */         \
    uint4 pv = *(const uint4*)(TBL + (size_t)v * 32 + f4);                          \
    float dv = dis[v];                                                              \
    int sreg  = esrc[beg + sub];                                                    \
    int sreg2 = esrc[beg + 16 + sub];                /* covered by +64 slack */     \
    int svals[16];                                                                  \
    _Pragma("unroll")                                                               \
    for (int it = 0; it < 4; it++) {                                                \
        svals[2 * it]     = __shfl(sreg,  nlb | (epar + 4 * it));                   \
        svals[2 * it + 1] = __shfl(sreg,  nlb | (epar + 4 * it + 2));               \
    }                                                                               \
    _Pragma("unroll")                                                               \
    for (int it = 4; it < 8; it++) {                                                \
        svals[2 * it]     = __shfl(sreg2, nlb | (epar + 4 * it - 16));              \
        svals[2 * it + 1] = __shfl(sreg2, nlb | (epar + 4 * it - 14));              \
    }                                                                               \
    float a0 = 0.f, a1 = 0.f, a2 = 0.f, a3 = 0.f, a4 = 0.f, a5 = 0.f, a6 = 0.f, a7 = 0.f; \
    float b0 = 0.f, b1 = 0.f, b2 = 0.f, b3 = 0.f, b4 = 0.f, b5 = 0.f, b6 = 0.f, b7 = 0.f; \
    int lim = nb < 32 ? nb : 32;                                                    \
    int nit = lim >> 2;                                                             \
    _Pragma("unroll")                                                               \
    for (int it = 0; it < 4; it++) {                                                \
        int s0 = (it < nit) ? svals[2 * it]     : NN;                               \
        int s1 = (it < nit) ? svals[2 * it + 1] : NN;                               \
        uint4 pA = *(const uint4*)(TBL + (size_t)s0 * 32 + f4);                     \
        uint4 pB = *(const uint4*)(TBL + (size_t)s1 * 32 + f4);                     \
        ACC8(a, pA); ACC8(b, pB);                                                   \
    }                                                                               \
    if (nb > 16) {                                   /* exec-masked per group */    \
        _Pragma("unroll")                                                           \
        for (int it = 4; it < 8; it++) {                                            \
            int s0 = (it < nit) ? svals[2 * it]     : NN;                           \
            int s1 = (it < nit) ? svals[2 * it + 1] : NN;                           \
            uint4 pA = *(const uint4*)(TBL + (size_t)s0 * 32 + f4);                 \
            uint4 pB = *(const uint4*)(TBL + (size_t)s1 * 32 + f4);                 \
            ACC8(a, pA); ACC8(b, pB);                                               \
        }                                                                           \
    }                                                                               \
    if (nb > 32) {                                                                  \
        for (int idx = 32 + epar; idx < nb; idx += 2) {   /* rare: degree > 32 */   \
            int s = esrc[beg + idx];                                                \
            uint4 p = *(const uint4*)(TBL + (size_t)s * 32 + f4);                   \
            ACC8(b, p);                                                             \
        }                                                                           \
    }                                                                               \
    a0 += b0; a1 += b1; a2 += b2; a3 += b3; a4 += b4; a5 += b5; a6 += b6; a7 += b7; \
    a0 += __shfl_xor(a0, 8); a1 += __shfl_xor(a1, 8);                               \
    a2 += __shfl_xor(a2, 8); a3 += __shfl_xor(a3, 8);                               \
    a4 += __shfl_xor(a4, 8); a5 += __shfl_xor(a5, 8);                               \
    a6 += __shfl_xor(a6, 8); a7 += __shfl_xor(a7, 8);                               \
    ACC8(a, pv);                                     /* self-loop once */

// ---------- aggregateX: axb[v] = bf16( dis_v * (sum_e xsb[s] + xsb[v]) ) ----------
__global__ __launch_bounds__(256) void aggregateX(const uint* __restrict__ xsb,  // [N+1,32]
                                                  const int2* __restrict__ prange,
                                                  const int* __restrict__ esrc,
                                                  const float* __restrict__ dis,
                                                  uint* __restrict__ axb) {
    GATHER_CORE(xsb)
    if (!epar) {
        uint4 o;
        o.x = pack2(dv * a0, dv * a1);
        o.y = pack2(dv * a2, dv * a3);
        o.z = pack2(dv * a4, dv * a5);
        o.w = pack2(dv * a6, dv * a7);
        *(uint4*)(axb + (size_t)v * 32 + f4) = o;
    }
}

__device__ __forceinline__ float selu_f(float v) {
    const float scale = 1.0507009873554805f;
    const float alpha = 1.6732632423543772f;
    return scale * (v > 0.f ? v : alpha * (expf(v) - 1.f));
}

// ---------- fused GEMM: hw2s = bf16( dis * ( selu(axb@W1 + b1) @ Wcat ) ) ----------
// 512 threads / 256 rows per block (halves per-block weight re-fetch traffic).
// Weights staged in LDS in frag-major order (conflict-free ds_read_b128 at
// frag*1024 + lane*16); H stays entirely in registers: stage-2's weight k-order is
// permuted (nofk) so stage-1's packed D-outputs ARE the stage-2 B-fragments.
__global__ __launch_bounds__(512) void gemm_fused(const uint* __restrict__ axb,
                                                  const ushort* __restrict__ Wall,
                                                  const float* __restrict__ b1,
                                                  const float* __restrict__ dis,
                                                  uint* __restrict__ hw2s) {
    __shared__ ushort Wlds[32768];   // 64 KB: W1hi | W1lo | Wchi | Wclo
    int tid = threadIdx.x;
    int lane = tid & 63;
    int xr = lane & 15, q = lane >> 4;
    int rowbase = blockIdx.x * 256 + (tid >> 6) * 16;
    int v0 = rowbase + xr;                // rowset 0
    int v1 = rowbase + 128 + xr;          // rowset 1
    int v0c = min(v0, NN - 1);
    int v1c = min(v1, NN - 1);

    // stage-1 B fragments (issue before staging copy so latency overlaps it)
    bf16x8 bf0[2], bf1[2];
#pragma unroll
    for (int ks = 0; ks < 2; ks++) {
        bf0[ks] = *(const bf16x8*)(axb + (size_t)v0c * 32 + ks * 16 + q * 4);
        bf1[ks] = *(const bf16x8*)(axb + (size_t)v1c * 32 + ks * 16 + q * 4);
    }

    // stage weights: linear 64KB copy, coalesced + conflict-free
    {
        const uint4* wsrc = (const uint4*)Wall;
        uint4* wdst = (uint4*)Wlds;
#pragma unroll
        for (int c = 0; c < 16; c++) wdst[tid + c * 512] = wsrc[tid + c * 512];
    }
    __syncthreads();

    const char* ldsb = (const char*)Wlds;
    int lane16 = lane * 16;

    // ---- stage 1: H^T tiles = W1T(A) x axb^T(B); selu; keep packed in regs ----
    uint px0[8], py0[8], px1[8], py1[8];
#pragma unroll
    for (int t = 0; t < 8; t++) {
        bf16x8 ah0 = *(const bf16x8*)(ldsb + (t * 2 + 0) * 1024 + lane16);
        bf16x8 ah1 = *(const bf16x8*)(ldsb + (t * 2 + 1) * 1024 + lane16);
        bf16x8 al0 = *(const bf16x8*)(ldsb + 16384 + (t * 2 + 0) * 1024 + lane16);
        bf16x8 al1 = *(const bf16x8*)(ldsb + 16384 + (t * 2 + 1) * 1024 + lane16);
        f32x4 acc0 = {0.f, 0.f, 0.f, 0.f};
        f32x4 acc1 = {0.f, 0.f, 0.f, 0.f};
        acc0 = MFMA16(ah0, bf0[0], acc0); acc0 = MFMA16(al0, bf0[0], acc0);
        acc0 = MFMA16(ah1, bf0[1], acc0); acc0 = MFMA16(al1, bf0[1], acc0);
        acc1 = MFMA16(ah0, bf1[0], acc1); acc1 = MFMA16(al0, bf1[0], acc1);
        acc1 = MFMA16(ah1, bf1[1], acc1); acc1 = MFMA16(al1, bf1[1], acc1);
        float4 bb = *(const float4*)(b1 + 16 * t + 4 * q);   // n = 16t+4q+r
        px0[t] = pack2(selu_f(acc0[0] + bb.x), selu_f(acc0[1] + bb.y));
        py0[t] = pack2(selu_f(acc0[2] + bb.z), selu_f(acc0[3] + bb.w));
        px1[t] = pack2(selu_f(acc1[0] + bb.x), selu_f(acc1[1] + bb.y));
        py1[t] = pack2(selu_f(acc1[2] + bb.z), selu_f(acc1[3] + bb.w));
    }

    // ---- stage 2: out^T tiles = WcT_perm(A) x H^T(B from regs); *dis epilogue ----
    float dv0 = dis[v0c], dv1 = dis[v1c];
#pragma unroll
    for (int t2 = 0; t2 < 4; t2++) {
        f32x4 a0 = {0.f, 0.f, 0.f, 0.f};
        f32x4 a1 = {0.f, 0.f, 0.f, 0.f};
#pragma unroll
        for (int ks = 0; ks < 4; ks++) {
            bf16x8 ah = *(const bf16x8*)(ldsb + 32768 + (t2 * 4 + ks) * 1024 + lane16);
            bf16x8 al = *(const bf16x8*)(ldsb + 49152 + (t2 * 4 + ks) * 1024 + lane16);
            bf16x8 fr0, fr1;
            *(uint4*)&fr0 = make_uint4(px0[2 * ks], py0[2 * ks], px0[2 * ks + 1], py0[2 * ks + 1]);
            *(uint4*)&fr1 = make_uint4(px1[2 * ks], py1[2 * ks], px1[2 * ks + 1], py1[2 * ks + 1]);
            a0 = MFMA16(ah, fr0, a0); a0 = MFMA16(al, fr0, a0);
            a1 = MFMA16(ah, fr1, a1); a1 = MFMA16(al, fr1, a1);
        }
        if (v0 < NN) {
            uint2 pk;
            pk.x = pack2(dv0 * a0[0], dv0 * a0[1]);
            pk.y = pack2(dv0 * a0[2], dv0 * a0[3]);
            *(uint2*)(hw2s + (size_t)v0 * 32 + t2 * 8 + q * 2) = pk;   // n = 16t2+4q..+3
        }
        if (v1 < NN) {
            uint2 pk;
            pk.x = pack2(dv1 * a1[0], dv1 * a1[1]);
            pk.y = pack2(dv1 * a1[2], dv1 * a1[3]);
            *(uint2*)(hw2s + (size_t)v1 * 32 + t2 * 8 + q * 2) = pk;
        }
    }
}

// ---------- aggregate2: gather core + bias + mu/lv split epilogue ----------
__global__ __launch_bounds__(256) void aggregate2(const uint* __restrict__ hw2s, // [N+1,32]
                                                  const int2* __restrict__ prange,
                                                  const int* __restrict__ esrc,
                                                  const float* __restrict__ dis,
                                                  const float* __restrict__ bmu,
                                                  const float* __restrict__ blv,
                                                  float* __restrict__ out) {
    GATHER_CORE(hw2s)
    if (!epar) {
        int j = sub & 7;                       // 0..7: feats 8j..8j+7
        const float* bp = (j < 4) ? (bmu + 8 * j) : (blv + 8 * j - 32);
        float* op = (j < 4) ? (out + (size_t)v * DOUT + 8 * j)
                            : (out + (size_t)NN * DOUT + (size_t)v * DOUT + 8 * j - 32);
        float4 c0 = *(const float4*)bp;
        float4 c1 = *(const float4*)(bp + 4);
        *(float4*)op       = make_float4(dv * a0 + c0.x, dv * a1 + c0.y,
                                         dv * a2 + c0.z, dv * a3 + c0.w);
        *(float4*)(op + 4) = make_float4(dv * a4 + c1.x, dv * a5 + c1.y,
                                         dv * a6 + c1.z, dv * a7 + c1.w);
    }
}

extern "C" void kernel_launch(void* const* d_in, const int* in_sizes, int n_in,
                              void* d_out, int out_size, void* d_ws, size_t ws_size,
                              hipStream_t stream) {
    const float* x   = (const float*)d_in[0];
    const int*   ei  = (const int*)d_in[1];
    const int*   e_src = ei;            // edge_index[0]
    const int*   e_dst = ei + NE;       // edge_index[1]
    const float* W1  = (const float*)d_in[2];
    const float* b1  = (const float*)d_in[3];
    const float* Wmu = (const float*)d_in[4];
    const float* bmu = (const float*)d_in[5];
    const float* Wlv = (const float*)d_in[6];
    const float* blv = (const float*)d_in[7];
    float* out = (float*)d_out;

    char* ws = (char*)d_ws;
    size_t off = 0;
    auto alloc = [&](size_t bytes) -> void* {
        void* p = ws + off;
        off += (bytes + 255) & ~(size_t)255;
        return p;
    };
    int2*   prange    = (int2*)alloc((size_t)NN * 8);
    int*    esrc      = (int*)alloc(((size_t)NBIN * PADESRC + 64) * 4);
    int*    cnt       = (int*)alloc((size_t)NBIN * NSEG * 4);
    int*    deg       = (int*)alloc((size_t)NN * 4);
    float*  dis       = (float*)alloc((size_t)NN * 4);
    ushort* Wall      = (ushort*)alloc((size_t)32768 * 2);        // frag-major weights, 64KB
    uint*   xb        = (uint*)alloc((size_t)(NN + 1) * 32 * 4);  // bf16 dis*x + zero row
    uint*   axb       = (uint*)alloc((size_t)NN * 32 * 4);        // bf16 A·x
    uint*   hw2s      = xb;            // xb dead after aggregateX; row NN stays zero
    uint*   ebin      = axb;           // axb unused until aggregateX; 12.53 MB <= 12.8 MB

    hipMemsetAsync(deg, 0, (size_t)NN * 4, stream);
    scatter_direct<<<NSEG, P1_THREADS, 0, stream>>>(e_src, e_dst, deg, ebin, cnt, NE);
    finalize_prep<<<NBIN, 512, 0, stream>>>(ebin, cnt, deg, x, W1, Wmu, Wlv,
                                            dis, prange, esrc, xb, Wall);
    aggregateX<<<NN / 16, 256, 0, stream>>>(xb, prange, esrc, dis, axb);
    gemm_fused<<<(NN + 255) / 256, 512, 0, stream>>>(axb, Wall, b1, dis, hw2s);
    aggregate2<<<NN / 16, 256, 0, stream>>>(hw2s, prange, esrc, dis, bmu, blv, out);
}

// Round 9
// 201.667 us; speedup vs baseline: 1.2001x; 1.2001x over previous
//
#include <hip/hip_runtime.h>
#include <math.h>

#define NN 100000
#define NE 1250000
#define DIN 64
#define DHID 128
#define DO2 64   // concat(mu|lv)
#define DOUT 32

#define NBIN 256
#define BINW ((NN + NBIN - 1) / NBIN)   // 391
#define NSEG 153                        // = ceil(NE / P1_EPB) scatter blocks
#define C2 80                           // per-(bin,block) cell capacity; binom(8192,1/256) mean 32, 8.5-sigma
#define PADESRC 10944                   // per-bin esrc region (max padded 8037), mult of 8
#define P1_THREADS 1024
#define P1_EPT 8
#define P1_EPB (P1_THREADS * P1_EPT)    // 8192

typedef unsigned int uint;
typedef unsigned short ushort;
typedef __attribute__((ext_vector_type(8))) short bf16x8;   // 8 bf16 = 4 VGPR (MFMA A/B frag)
typedef __attribute__((ext_vector_type(4))) float f32x4;    // MFMA C/D frag

#define MFMA16(A, B, C) __builtin_amdgcn_mfma_f32_16x16x32_bf16(A, B, C, 0, 0, 0)

__device__ __forceinline__ ushort f2bf(float f) {
    uint u = __float_as_uint(f);
    uint r = (u + 0x7fffu + ((u >> 16) & 1u)) >> 16;   // RNE
    return (ushort)r;
}
__device__ __forceinline__ uint pack2(float a, float b) {
    return (uint)f2bf(a) | ((uint)f2bf(b) << 16);
}
__device__ __forceinline__ float bflo(uint p) { return __uint_as_float(p << 16); }
__device__ __forceinline__ float bfhi(uint p) { return __uint_as_float(p & 0xffff0000u); }

// stage2 k-permutation: feature index fed at MFMA k-position k.
// k bits: [ks:5-6 | q:3-4 | j:0-2]  ->  n = 32ks + 16*(j>>2) + 4q + (j&3)
__device__ __forceinline__ int nofk(int k) {
    return (k & 3) | (((k >> 3) & 3) << 2) | (((k >> 2) & 1) << 4) | ((k >> 5) << 5);
}

// accumulate 8 bf16 features from a packed uint4 row segment
#define ACC8(A, P) do { \
    A##0 += bflo((P).x); A##1 += bfhi((P).x); \
    A##2 += bflo((P).y); A##3 += bfhi((P).y); \
    A##4 += bflo((P).z); A##5 += bfhi((P).z); \
    A##6 += bflo((P).w); A##7 += bfhi((P).w); } while (0)

// ---------- direct scatter into per-(bin,block) private cells — no global cursors ----------
// ebin[(b*NSEG + blk)*C2 + rank] = (src<<9)|localdst ; cnt[b*NSEG + blk] = count.
// (R8 lesson: NO per-edge global atomics — degree comes from finalize's cell-hist.)
__global__ __launch_bounds__(P1_THREADS) void scatter_direct(const int* __restrict__ src,
                                                             const int* __restrict__ dst,
                                                             uint* __restrict__ ebin,
                                                             int* __restrict__ cnt, int n) {
    __shared__ int hist[NBIN];
    int tid = threadIdx.x;
    if (tid < NBIN) hist[tid] = 0;
    __syncthreads();
    int bi = blockIdx.x;
    int base = bi * P1_EPB;
#pragma unroll
    for (int j = 0; j < P1_EPT; j++) {
        int i = base + j * P1_THREADS + tid;
        if (i < n) {
            int d = dst[i];
            int bb = d / BINW;
            uint e = ((uint)src[i] << 9) | (uint)(d - bb * BINW);
            int rk = atomicAdd(&hist[bb], 1);
            if (rk < C2) ebin[((size_t)bb * NSEG + bi) * C2 + rk] = e;
        }
    }
    __syncthreads();
    if (tid < NBIN) cnt[tid * NSEG + bi] = min(hist[tid], C2);
}

// ---------- merged finalize: cell-hist -> dis/prange/esrc scatter + x-cast + weight prep ----
// xb flat: [node][32 uints] = bf16 feats (row NN = zero padding target).
// Weight layout (ushort idx in Wall):
//   [0,8192)      W1 hi  frag fr=t*2+ks: [(fr*64+lane)*8+e] = hi(W1[k*DHID+row]),
//                 row=16t+(lane&15), k=ks*32+(lane>>4)*8+e
//   [8192,16384)  W1 lo (residual)
//   [16384,24576) Wc hi  frag fr=t2*4+ks: nout=16t2+(lane&15), kpos=ks*32+(lane>>4)*8+e,
//                 h=nofk(kpos), hi(Wcat[h][nout]); Wcat = concat cols (Wmu|Wlv)
//   [24576,32768) Wc lo
__global__ __launch_bounds__(512) void finalize_prep(const uint* __restrict__ ebin,
                                                     const int* __restrict__ cnt,
                                                     const float* __restrict__ x,
                                                     const float* __restrict__ W1,
                                                     const float* __restrict__ Wmu,
                                                     const float* __restrict__ Wlv,
                                                     float* __restrict__ dis,
                                                     int2* __restrict__ prange,
                                                     int* __restrict__ esrc,
                                                     uint* __restrict__ xb,
                                                     ushort* __restrict__ Wall) {
    __shared__ int hh[BINW];
    __shared__ int base_s[BINW];
    __shared__ int cur_s[BINW];
    __shared__ float dd[BINW];
    int b = blockIdx.x;
    int tid = threadIdx.x;
    int v0 = b * BINW;
    int nv = min(BINW, NN - v0);
    int pbase = PADESRC * b;                        // 8-aligned by construction
    for (int i = tid; i < BINW; i += 512) { hh[i] = 0; cur_s[i] = 0; }
    __syncthreads();
    int wv = tid >> 6, ln = tid & 63;
    // node-degree hist over this bin's cells
    for (int s = wv; s < NSEG; s += 8) {
        int m = cnt[b * NSEG + s];
        const uint* cell = ebin + ((size_t)b * NSEG + s) * C2;
        for (int j = ln; j < m; j += 64)
            atomicAdd(&hh[cell[j] & 511u], 1);
    }
    __syncthreads();
    int c = (tid < nv) ? hh[tid] : 0;
    int p = (c + 7) & ~7;
    __syncthreads();
    if (tid < nv) hh[tid] = p;
    __syncthreads();
    for (int off = 1; off < BINW; off <<= 1) {      // inclusive scan of padded counts
        int t = (tid < nv && tid >= off) ? hh[tid - off] : 0;
        __syncthreads();
        if (tid < nv) hh[tid] += t;
        __syncthreads();
    }
    if (tid < nv) {
        int base = pbase + hh[tid] - p;
        base_s[tid] = base;
        prange[v0 + tid] = make_int2(base, base + p);
        float dv = rsqrtf((float)c + 1.0f);
        dis[v0 + tid] = dv;
        dd[tid] = dv;
        for (int j = c; j < p; j++) esrc[base + j] = NN;   // node tail padding
    }
    __syncthreads();
    // scatter src indices (ebin cells L2-hot from hist pass)
    for (int s = wv; s < NSEG; s += 8) {
        int m = cnt[b * NSEG + s];
        const uint* cell = ebin + ((size_t)b * NSEG + s) * C2;
        for (int j = ln; j < m; j += 64) {
            uint e = cell[j];
            int l = (int)(e & 511u);
            int pos = base_s[l] + atomicAdd(&cur_s[l], 1);
            esrc[pos] = (int)(e >> 9);
        }
    }
    // cast + pre-scale this bin's x rows: xb[row] = bf16(dis_row * x[row])
    for (int idx = tid; idx < nv * 8; idx += 512) {
        int r = idx >> 3, q = idx & 7;
        float dv = dd[r];
        int row = v0 + r;
        const float4* xs = (const float4*)(x + (size_t)row * 64 + q * 8);
        float4 u0 = xs[0], u1 = xs[1];
        uint4 o;
        o.x = pack2(dv * u0.x, dv * u0.y);
        o.y = pack2(dv * u0.z, dv * u0.w);
        o.z = pack2(dv * u1.x, dv * u1.y);
        o.w = pack2(dv * u1.z, dv * u1.w);
        *(uint4*)(xb + (size_t)row * 32 + q * 4) = o;
    }
    if (b == NBIN - 1 && tid < 32) xb[(size_t)NN * 32 + tid] = 0;   // zero padding row
    // weight prep: 64 items per block
    if (tid < 64) {
        int i = b * 64 + tid;                        // < 16384
        if (i < 8192) {
            int lane = (i >> 3) & 63, e = i & 7;
            int fr = i >> 9;                 // t*2+ks
            int t = fr >> 1, ks = fr & 1;
            int row = 16 * t + (lane & 15);
            int k = ks * 32 + (lane >> 4) * 8 + e;
            float w = W1[k * DHID + row];
            ushort hi = f2bf(w);
            Wall[i] = hi;
            Wall[8192 + i] = f2bf(w - bflo((uint)hi));
        } else {
            int ii = i - 8192;
            int lane = (ii >> 3) & 63, e = ii & 7;
            int fr = ii >> 9;                // t2*4+ks
            int t2 = fr >> 2, ks = fr & 3;
            int nout = 16 * t2 + (lane & 15);
            int kpos = ks * 32 + (lane >> 4) * 8 + e;
            int h = nofk(kpos);
            float w = (nout < DOUT) ? Wmu[h * DOUT + nout] : Wlv[h * DOUT + (nout - DOUT)];
            ushort hi = f2bf(w);
            Wall[16384 + ii] = hi;
            Wall[24576 + ii] = f2bf(w - bflo((uint)hi));
        }
    }
}

// ---------- 16-lanes-per-node gather core (4 nodes/wave), batched loads ----------
// Lane bits: [5:4]=node group, [3]=edge-parallel slot, [2:0]=feature quad.
// All 16 shfls hoisted into svals; first 8 row-loads issued into NAMED registers
// BEFORE any accumulation (keeps 8 gathers in flight per wave — the 20-VGPR
// versions held only ~2). Second batch of 8 under per-lane nb>16 predicate
// (deg uniform per 16-lane group -> exec-masked skip). Clamped slots read the
// maintained zero row NN (L1-hot). Self-loop pv ADDED ONCE post-reduce (R3).
#define GATHER_CORE(TBL)                                                            \
    int tid = threadIdx.x;                                                          \
    int lane = tid & 63;                                                            \
    int sub = lane & 15;                                                            \
    int epar = sub >> 3;                                                            \
    int f4 = (sub & 7) * 4;                                                         \
    int nlb = lane & 48;                                                            \
    int v = blockIdx.x * 16 + (tid >> 4);            /* NN = 6250*16 exactly */     \
    int2 rng = prange[v];                                                           \
    int beg = rng.x, nb = rng.y - rng.x;             /* nb multiple of 8 */         \
    uint4 pv = *(const uint4*)(TBL + (size_t)v * 32 + f4);                          \
    float dv = dis[v];                                                              \
    int sreg  = esrc[beg + sub];                                                    \
    int sreg2 = esrc[beg + 16 + sub];                /* covered by +64 slack */     \
    int svals[16];                                                                  \
    _Pragma("unroll")                                                               \
    for (int it = 0; it < 4; it++) {                                                \
        svals[2 * it]     = __shfl(sreg,  nlb | (epar + 4 * it));                   \
        svals[2 * it + 1] = __shfl(sreg,  nlb | (epar + 4 * it + 2));               \
    }                                                                               \
    _Pragma("unroll")                                                               \
    for (int it = 4; it < 8; it++) {                                                \
        svals[2 * it]     = __shfl(sreg2, nlb | (epar + 4 * it - 16));              \
        svals[2 * it + 1] = __shfl(sreg2, nlb | (epar + 4 * it - 14));              \
    }                                                                               \
    float a0 = 0.f, a1 = 0.f, a2 = 0.f, a3 = 0.f, a4 = 0.f, a5 = 0.f, a6 = 0.f, a7 = 0.f; \
    float b0 = 0.f, b1 = 0.f, b2 = 0.f, b3 = 0.f, b4 = 0.f, b5 = 0.f, b6 = 0.f, b7 = 0.f; \
    int lim = nb < 32 ? nb : 32;                                                    \
    int nit = lim >> 2;                              /* even: 0,2,4,6,8 */          \
    {                                                /* batch 1: 8 loads in flight */ \
        int s0 = (0 < nit) ? svals[0] : NN;                                         \
        int s1 = (0 < nit) ? svals[1] : NN;                                         \
        int s2 = (1 < nit) ? svals[2] : NN;                                         \
        int s3 = (1 < nit) ? svals[3] : NN;                                         \
        int s4 = (2 < nit) ? svals[4] : NN;                                         \
        int s5 = (2 < nit) ? svals[5] : NN;                                         \
        int s6 = (3 < nit) ? svals[6] : NN;                                         \
        int s7 = (3 < nit) ? svals[7] : NN;                                         \
        uint4 p0 = *(const uint4*)(TBL + (size_t)s0 * 32 + f4);                     \
        uint4 p1 = *(const uint4*)(TBL + (size_t)s1 * 32 + f4);                     \
        uint4 p2 = *(const uint4*)(TBL + (size_t)s2 * 32 + f4);                     \
        uint4 p3 = *(const uint4*)(TBL + (size_t)s3 * 32 + f4);                     \
        uint4 p4 = *(const uint4*)(TBL + (size_t)s4 * 32 + f4);                     \
        uint4 p5 = *(const uint4*)(TBL + (size_t)s5 * 32 + f4);                     \
        uint4 p6 = *(const uint4*)(TBL + (size_t)s6 * 32 + f4);                     \
        uint4 p7 = *(const uint4*)(TBL + (size_t)s7 * 32 + f4);                     \
        ACC8(a, p0); ACC8(b, p1); ACC8(a, p2); ACC8(b, p3);                         \
        ACC8(a, p4); ACC8(b, p5); ACC8(a, p6); ACC8(b, p7);                         \
    }                                                                               \
    if (nb > 16) {                                   /* batch 2, exec-masked */     \
        int s0 = (4 < nit) ? svals[8]  : NN;                                        \
        int s1 = (4 < nit) ? svals[9]  : NN;                                        \
        int s2 = (5 < nit) ? svals[10] : NN;                                        \
        int s3 = (5 < nit) ? svals[11] : NN;                                        \
        int s4 = (6 < nit) ? svals[12] : NN;                                        \
        int s5 = (6 < nit) ? svals[13] : NN;                                        \
        int s6 = (7 < nit) ? svals[14] : NN;                                        \
        int s7 = (7 < nit) ? svals[15] : NN;                                        \
        uint4 p0 = *(const uint4*)(TBL + (size_t)s0 * 32 + f4);                     \
        uint4 p1 = *(const uint4*)(TBL + (size_t)s1 * 32 + f4);                     \
        uint4 p2 = *(const uint4*)(TBL + (size_t)s2 * 32 + f4);                     \
        uint4 p3 = *(const uint4*)(TBL + (size_t)s3 * 32 + f4);                     \
        uint4 p4 = *(const uint4*)(TBL + (size_t)s4 * 32 + f4);                     \
        uint4 p5 = *(const uint4*)(TBL + (size_t)s5 * 32 + f4);                     \
        uint4 p6 = *(const uint4*)(TBL + (size_t)s6 * 32 + f4);                     \
        uint4 p7 = *(const uint4*)(TBL + (size_t)s7 * 32 + f4);                     \
        ACC8(a, p0); ACC8(b, p1); ACC8(a, p2); ACC8(b, p3);                         \
        ACC8(a, p4); ACC8(b, p5); ACC8(a, p6); ACC8(b, p7);                         \
    }                                                                               \
    if (nb > 32) {                                                                  \
        for (int idx = 32 + epar; idx < nb; idx += 2) {   /* rare: degree > 32 */   \
            int s = esrc[beg + idx];                                                \
            uint4 p = *(const uint4*)(TBL + (size_t)s * 32 + f4);                   \
            ACC8(b, p);                                                             \
        }                                                                           \
    }                                                                               \
    a0 += b0; a1 += b1; a2 += b2; a3 += b3; a4 += b4; a5 += b5; a6 += b6; a7 += b7; \
    a0 += __shfl_xor(a0, 8); a1 += __shfl_xor(a1, 8);                               \
    a2 += __shfl_xor(a2, 8); a3 += __shfl_xor(a3, 8);                               \
    a4 += __shfl_xor(a4, 8); a5 += __shfl_xor(a5, 8);                               \
    a6 += __shfl_xor(a6, 8); a7 += __shfl_xor(a7, 8);                               \
    ACC8(a, pv);                                     /* self-loop once */

// ---------- aggregateX: axb[v] = bf16( dis_v * (sum_e xsb[s] + xsb[v]) ) ----------
__global__ __launch_bounds__(256) void aggregateX(const uint* __restrict__ xsb,  // [N+1,32]
                                                  const int2* __restrict__ prange,
                                                  const int* __restrict__ esrc,
                                                  const float* __restrict__ dis,
                                                  uint* __restrict__ axb) {
    GATHER_CORE(xsb)
    if (!epar) {
        uint4 o;
        o.x = pack2(dv * a0, dv * a1);
        o.y = pack2(dv * a2, dv * a3);
        o.z = pack2(dv * a4, dv * a5);
        o.w = pack2(dv * a6, dv * a7);
        *(uint4*)(axb + (size_t)v * 32 + f4) = o;
    }
}

__device__ __forceinline__ float selu_f(float v) {
    const float scale = 1.0507009873554805f;
    const float alpha = 1.6732632423543772f;
    return scale * (v > 0.f ? v : alpha * (expf(v) - 1.f));
}

// ---------- fused GEMM: hw2s = bf16( dis * ( selu(axb@W1 + b1) @ Wcat ) ) ----------
// 512 threads / 256 rows per block (halves per-block weight re-fetch traffic).
// Weights staged in LDS in frag-major order (conflict-free ds_read_b128 at
// frag*1024 + lane*16); H stays entirely in registers: stage-2's weight k-order is
// permuted (nofk) so stage-1's packed D-outputs ARE the stage-2 B-fragments.
__global__ __launch_bounds__(512) void gemm_fused(const uint* __restrict__ axb,
                                                  const ushort* __restrict__ Wall,
                                                  const float* __restrict__ b1,
                                                  const float* __restrict__ dis,
                                                  uint* __restrict__ hw2s) {
    __shared__ ushort Wlds[32768];   // 64 KB: W1hi | W1lo | Wchi | Wclo
    int tid = threadIdx.x;
    int lane = tid & 63;
    int xr = lane & 15, q = lane >> 4;
    int rowbase = blockIdx.x * 256 + (tid >> 6) * 16;
    int v0 = rowbase + xr;                // rowset 0
    int v1 = rowbase + 128 + xr;          // rowset 1
    int v0c = min(v0, NN - 1);
    int v1c = min(v1, NN - 1);

    // stage-1 B fragments (issue before staging copy so latency overlaps it)
    bf16x8 bf0[2], bf1[2];
#pragma unroll
    for (int ks = 0; ks < 2; ks++) {
        bf0[ks] = *(const bf16x8*)(axb + (size_t)v0c * 32 + ks * 16 + q * 4);
        bf1[ks] = *(const bf16x8*)(axb + (size_t)v1c * 32 + ks * 16 + q * 4);
    }

    // stage weights: linear 64KB copy, coalesced + conflict-free
    {
        const uint4* wsrc = (const uint4*)Wall;
        uint4* wdst = (uint4*)Wlds;
#pragma unroll
        for (int c = 0; c < 16; c++) wdst[tid + c * 512] = wsrc[tid + c * 512];
    }
    __syncthreads();

    const char* ldsb = (const char*)Wlds;
    int lane16 = lane * 16;

    // ---- stage 1: H^T tiles = W1T(A) x axb^T(B); selu; keep packed in regs ----
    uint px0[8], py0[8], px1[8], py1[8];
#pragma unroll
    for (int t = 0; t < 8; t++) {
        bf16x8 ah0 = *(const bf16x8*)(ldsb + (t * 2 + 0) * 1024 + lane16);
        bf16x8 ah1 = *(const bf16x8*)(ldsb + (t * 2 + 1) * 1024 + lane16);
        bf16x8 al0 = *(const bf16x8*)(ldsb + 16384 + (t * 2 + 0) * 1024 + lane16);
        bf16x8 al1 = *(const bf16x8*)(ldsb + 16384 + (t * 2 + 1) * 1024 + lane16);
        f32x4 acc0 = {0.f, 0.f, 0.f, 0.f};
        f32x4 acc1 = {0.f, 0.f, 0.f, 0.f};
        acc0 = MFMA16(ah0, bf0[0], acc0); acc0 = MFMA16(al0, bf0[0], acc0);
        acc0 = MFMA16(ah1, bf0[1], acc0); acc0 = MFMA16(al1, bf0[1], acc0);
        acc1 = MFMA16(ah0, bf1[0], acc1); acc1 = MFMA16(al0, bf1[0], acc1);
        acc1 = MFMA16(ah1, bf1[1], acc1); acc1 = MFMA16(al1, bf1[1], acc1);
        float4 bb = *(const float4*)(b1 + 16 * t + 4 * q);   // n = 16t+4q+r
        px0[t] = pack2(selu_f(acc0[0] + bb.x), selu_f(acc0[1] + bb.y));
        py0[t] = pack2(selu_f(acc0[2] + bb.z), selu_f(acc0[3] + bb.w));
        px1[t] = pack2(selu_f(acc1[0] + bb.x), selu_f(acc1[1] + bb.y));
        py1[t] = pack2(selu_f(acc1[2] + bb.z), selu_f(acc1[3] + bb.w));
    }

    // ---- stage 2: out^T tiles = WcT_perm(A) x H^T(B from regs); *dis epilogue ----
    float dv0 = dis[v0c], dv1 = dis[v1c];
#pragma unroll
    for (int t2 = 0; t2 < 4; t2++) {
        f32x4 a0 = {0.f, 0.f, 0.f, 0.f};
        f32x4 a1 = {0.f, 0.f, 0.f, 0.f};
#pragma unroll
        for (int ks = 0; ks < 4; ks++) {
            bf16x8 ah = *(const bf16x8*)(ldsb + 32768 + (t2 * 4 + ks) * 1024 + lane16);
            bf16x8 al = *(const bf16x8*)(ldsb + 49152 + (t2 * 4 + ks) * 1024 + lane16);
            bf16x8 fr0, fr1;
            *(uint4*)&fr0 = make_uint4(px0[2 * ks], py0[2 * ks], px0[2 * ks + 1], py0[2 * ks + 1]);
            *(uint4*)&fr1 = make_uint4(px1[2 * ks], py1[2 * ks], px1[2 * ks + 1], py1[2 * ks + 1]);
            a0 = MFMA16(ah, fr0, a0); a0 = MFMA16(al, fr0, a0);
            a1 = MFMA16(ah, fr1, a1); a1 = MFMA16(al, fr1, a1);
        }
        if (v0 < NN) {
            uint2 pk;
            pk.x = pack2(dv0 * a0[0], dv0 * a0[1]);
            pk.y = pack2(dv0 * a0[2], dv0 * a0[3]);
            *(uint2*)(hw2s + (size_t)v0 * 32 + t2 * 8 + q * 2) = pk;   // n = 16t2+4q..+3
        }
        if (v1 < NN) {
            uint2 pk;
            pk.x = pack2(dv1 * a1[0], dv1 * a1[1]);
            pk.y = pack2(dv1 * a1[2], dv1 * a1[3]);
            *(uint2*)(hw2s + (size_t)v1 * 32 + t2 * 8 + q * 2) = pk;
        }
    }
}

// ---------- aggregate2: gather core + bias + mu/lv split epilogue ----------
__global__ __launch_bounds__(256) void aggregate2(const uint* __restrict__ hw2s, // [N+1,32]
                                                  const int2* __restrict__ prange,
                                                  const int* __restrict__ esrc,
                                                  const float* __restrict__ dis,
                                                  const float* __restrict__ bmu,
                                                  const float* __restrict__ blv,
                                                  float* __restrict__ out) {
    GATHER_CORE(hw2s)
    if (!epar) {
        int j = sub & 7;                       // 0..7: feats 8j..8j+7
        const float* bp = (j < 4) ? (bmu + 8 * j) : (blv + 8 * j - 32);
        float* op = (j < 4) ? (out + (size_t)v * DOUT + 8 * j)
                            : (out + (size_t)NN * DOUT + (size_t)v * DOUT + 8 * j - 32);
        float4 c0 = *(const float4*)bp;
        float4 c1 = *(const float4*)(bp + 4);
        *(float4*)op       = make_float4(dv * a0 + c0.x, dv * a1 + c0.y,
                                         dv * a2 + c0.z, dv * a3 + c0.w);
        *(float4*)(op + 4) = make_float4(dv * a4 + c1.x, dv * a5 + c1.y,
                                         dv * a6 + c1.z, dv * a7 + c1.w);
    }
}

extern "C" void kernel_launch(void* const* d_in, const int* in_sizes, int n_in,
                              void* d_out, int out_size, void* d_ws, size_t ws_size,
                              hipStream_t stream) {
    const float* x   = (const float*)d_in[0];
    const int*   ei  = (const int*)d_in[1];
    const int*   e_src = ei;            // edge_index[0]
    const int*   e_dst = ei + NE;       // edge_index[1]
    const float* W1  = (const float*)d_in[2];
    const float* b1  = (const float*)d_in[3];
    const float* Wmu = (const float*)d_in[4];
    const float* bmu = (const float*)d_in[5];
    const float* Wlv = (const float*)d_in[6];
    const float* blv = (const float*)d_in[7];
    float* out = (float*)d_out;

    char* ws = (char*)d_ws;
    size_t off = 0;
    auto alloc = [&](size_t bytes) -> void* {
        void* p = ws + off;
        off += (bytes + 255) & ~(size_t)255;
        return p;
    };
    int2*   prange    = (int2*)alloc((size_t)NN * 8);
    int*    esrc      = (int*)alloc(((size_t)NBIN * PADESRC + 64) * 4);
    int*    cnt       = (int*)alloc((size_t)NBIN * NSEG * 4);
    float*  dis       = (float*)alloc((size_t)NN * 4);
    ushort* Wall      = (ushort*)alloc((size_t)32768 * 2);        // frag-major weights, 64KB
    uint*   xb        = (uint*)alloc((size_t)(NN + 1) * 32 * 4);  // bf16 dis*x + zero row
    uint*   axb       = (uint*)alloc((size_t)NN * 32 * 4);        // bf16 A·x
    uint*   hw2s      = xb;            // xb dead after aggregateX; row NN stays zero
    uint*   ebin      = axb;           // axb unused until aggregateX; 12.53 MB <= 12.8 MB

    scatter_direct<<<NSEG, P1_THREADS, 0, stream>>>(e_src, e_dst, ebin, cnt, NE);
    finalize_prep<<<NBIN, 512, 0, stream>>>(ebin, cnt, x, W1, Wmu, Wlv,
                                            dis, prange, esrc, xb, Wall);
    aggregateX<<<NN / 16, 256, 0, stream>>>(xb, prange, esrc, dis, axb);
    gemm_fused<<<(NN + 255) / 256, 512, 0, stream>>>(axb, Wall, b1, dis, hw2s);
    aggregate2<<<NN / 16, 256, 0, stream>>>(hw2s, prange, esrc, dis, bmu, blv, out);
}